// Round 12
// baseline (168.748 us; speedup 1.0000x reference)
//
#include <hip/hip_runtime.h>
#include <math.h>

#define N_NODES 100000
#define N_EDGES 1600000
#define NB_SCAN 391   // ceil(N_NODES/256)
#define CHUNK 4096
#define NCHA 391      // ceil(N_EDGES/CHUNK)
#define NBUK 256      // coarse dst buckets
#define DPB 391       // dsts per bucket (256*391 = 100096 >= 100000)
#define BSTRIDE 7168  // per-bucket capacity (mean 6250, sigma ~79)
#define TILE_N 25000  // src tile (3.2 MB bf16, fits 4 MB XCD L2)

typedef __attribute__((ext_vector_type(8))) short bf16x8;
typedef __attribute__((ext_vector_type(4))) float f32x4;

__device__ __forceinline__ unsigned short f2bf(float f) {
    union { float f; unsigned u; } v; v.f = f;
    unsigned r = v.u + 0x7FFF + ((v.u >> 16) & 1);  // round-nearest-even
    return (unsigned short)(r >> 16);
}
__device__ __forceinline__ float bf2f(unsigned short b) {
    union { unsigned u; float f; } v; v.u = ((unsigned)b) << 16;
    return v.f;
}

// ---------------------------------------------------------------------------
// f32 -> bf16 row copy of x (for the gather path).
// ---------------------------------------------------------------------------
__global__ void x2bf16_kernel(const float* __restrict__ x,
                              unsigned short* __restrict__ xb) {
    int i = blockIdx.x * 256 + threadIdx.x;
    if (i >= N_NODES * 16) return;
    float4 v = reinterpret_cast<const float4*>(x)[i];
    ushort4 o;
    o.x = f2bf(v.x); o.y = f2bf(v.y); o.z = f2bf(v.z); o.w = f2bf(v.w);
    reinterpret_cast<ushort4*>(xb)[i] = o;
}

// ---------------------------------------------------------------------------
// Weight transpose+cast: Wt[c][k] = {W[0],W[1],root}[k][c], bf16; pad rows 0.
// ---------------------------------------------------------------------------
__global__ void wt_kernel(const float* __restrict__ W, const float* __restrict__ root,
                          unsigned short* __restrict__ Wt, int COUT, int total) {
    int i = blockIdx.x * 256 + threadIdx.x;
    if (i >= total) return;
    int c = i / 192;
    int k = i - c * 192;
    float v = 0.0f;
    if (c < COUT)
        v = (k < 128) ? W[(k >> 6) * 64 * COUT + (k & 63) * COUT + c]
                      : root[(k - 128) * COUT + c];
    Wt[i] = f2bf(v);
}

// ---------------------------------------------------------------------------
// Phase A: bin edges into 256 coarse dst-buckets with LDS compaction, so all
// global writes are contiguous runs. Record: {src, u16<<16 | dst_local(10b)}.
// ---------------------------------------------------------------------------
__global__ __launch_bounds__(256) void bin_edges(const int* __restrict__ ei,
                                                 const float* __restrict__ ea,
                                                 int* __restrict__ bucket_cur,
                                                 int2* __restrict__ binned) {
    __shared__ int hist[NBUK];
    __shared__ int lbase[NBUK];
    __shared__ int lcur[NBUK];
    __shared__ int gbase[NBUK];
    __shared__ int2 stage[CHUNK];
    __shared__ unsigned char sbkt[CHUNK];
    int tid = threadIdx.x;
    int e0 = blockIdx.x * CHUNK;
    int nval = min(CHUNK, N_EDGES - e0);

    if (tid < NBUK) hist[tid] = 0;
    __syncthreads();
    for (int j = tid; j < nval; j += 256)
        atomicAdd(&hist[ei[N_EDGES + e0 + j] / DPB], 1);
    __syncthreads();
    if (tid < NBUK) lbase[tid] = hist[tid];
    __syncthreads();
    for (int off = 1; off < NBUK; off <<= 1) {
        int v = (tid < NBUK && tid >= off) ? lbase[tid - off] : 0;
        __syncthreads();
        if (tid < NBUK) lbase[tid] += v;
        __syncthreads();
    }
    if (tid < NBUK) {
        int ex = lbase[tid] - hist[tid];  // exclusive
        lbase[tid] = ex;
        lcur[tid]  = ex;
        gbase[tid] = atomicAdd(&bucket_cur[tid], hist[tid]);
    }
    __syncthreads();
    for (int j = tid; j < nval; j += 256) {
        int e = e0 + j;
        int d = ei[N_EDGES + e];
        int b = d / DPB;
        int dl = d - b * DPB;
        float u = ea[e];
        int uq = min((int)(u * 65536.0f + 0.5f), 65535);
        int pos = atomicAdd(&lcur[b], 1);
        stage[pos] = make_int2(ei[e], (uq << 16) | dl);
        sbkt[pos] = (unsigned char)b;
    }
    __syncthreads();
    for (int j = tid; j < nval; j += 256) {
        int b = sbkt[j];
        int gp = gbase[b] + (j - lbase[b]);
        if (gp < BSTRIDE)
            binned[(size_t)b * BSTRIDE + gp] = stage[j];
    }
}

// ---------------------------------------------------------------------------
// Phase B: per-bucket counting sort over key = dst_local*4 + src_tile.
// Emits rowptr[d], cnt[d], packed 4B rec = (src<<15 | u15), and the per-node
// degree-bin info + per-bucket bin offsets for the balance permutation.
// ---------------------------------------------------------------------------
__global__ __launch_bounds__(512) void bucket_sort(const int* __restrict__ bucket_cur,
                                                   const int2* __restrict__ binned,
                                                   unsigned* __restrict__ rec,
                                                   int* __restrict__ rowptr,
                                                   int* __restrict__ cnt_g,
                                                   int* __restrict__ bin_cnt,
                                                   int* __restrict__ bin_rel,
                                                   int* __restrict__ nodeinfo) {
    __shared__ int keycnt[1600];
    __shared__ int tsum[512];
    __shared__ int dh[64];
    __shared__ unsigned stage[BSTRIDE];
    int tid = threadIdx.x;
    int b = blockIdx.x;

    // global base of this bucket = exclusive prefix of bucket sizes
    tsum[tid] = (tid < NBUK) ? bucket_cur[tid] : 0;
    __syncthreads();
    for (int off = 1; off < 512; off <<= 1) {
        int v = (tid >= off) ? tsum[tid - off] : 0;
        __syncthreads();
        tsum[tid] += v;
        __syncthreads();
    }
    int base = (b == 0) ? 0 : tsum[b - 1];
    int m = min(bucket_cur[b], BSTRIDE);
    __syncthreads();

    for (int k = tid; k < 1600; k += 512) keycnt[k] = 0;
    if (tid < 64) dh[tid] = 0;
    __syncthreads();
    const int2* bin = binned + (size_t)b * BSTRIDE;
    for (int j = tid; j < m; j += 512) {
        int2 r = bin[j];
        int key = ((r.y & 1023) << 2) | ((unsigned)r.x / TILE_N);
        atomicAdd(&keycnt[key], 1);
    }
    __syncthreads();
    int k0 = tid << 2;
    int c0 = 0, c1 = 0, c2 = 0, c3 = 0;
    if (tid < DPB) {
        c0 = keycnt[k0]; c1 = keycnt[k0 + 1];
        c2 = keycnt[k0 + 2]; c3 = keycnt[k0 + 3];
    }
    int s4 = c0 + c1 + c2 + c3;
    tsum[tid] = s4;
    __syncthreads();
    for (int off = 1; off < 512; off <<= 1) {
        int v = (tid >= off) ? tsum[tid - off] : 0;
        __syncthreads();
        tsum[tid] += v;
        __syncthreads();
    }
    bool isnode = (tid < DPB) && (b * DPB + tid < N_NODES);
    int binid = 0, lpos = 0;
    if (tid < DPB) {
        int p = tsum[tid] - s4;  // exclusive over keys
        int d = b * DPB + tid;
        if (d < N_NODES) {
            rowptr[d] = base + p;
            cnt_g[d]  = s4;
        }
        keycnt[k0] = p;     p += c0;
        keycnt[k0 + 1] = p; p += c1;
        keycnt[k0 + 2] = p; p += c2;
        keycnt[k0 + 3] = p;
        if (isnode) {
            binid = min(s4, 63);
            lpos = atomicAdd(&dh[binid], 1);
        }
    }
    __syncthreads();
    // degree-bin global offsets (for balance permutation)
    if (tid < 64) bin_rel[b * 64 + tid] = atomicAdd(&bin_cnt[tid], dh[tid]);
    if (isnode) nodeinfo[b * DPB + tid] = (binid << 9) | lpos;
    // place sorted (packed 4B) into LDS
    for (int j = tid; j < m; j += 512) {
        int2 r = bin[j];
        int key = ((r.y & 1023) << 2) | ((unsigned)r.x / TILE_N);
        unsigned uq15 = ((unsigned)r.y >> 17);  // 15-bit u
        int pos = atomicAdd(&keycnt[key], 1);
        if (pos < BSTRIDE) stage[pos] = ((unsigned)r.x << 15) | uq15;
    }
    __syncthreads();
    for (int j = tid; j < m; j += 512)
        rec[base + j] = stage[j];
}

// ---------------------------------------------------------------------------
// Degree-bin scan (64 bins, single block) -> exclusive bin_base.
// ---------------------------------------------------------------------------
__global__ void scan64(const int* __restrict__ bin_cnt, int* __restrict__ bin_base) {
    __shared__ int s[64];
    int t = threadIdx.x;
    int v = bin_cnt[t];
    s[t] = v;
    __syncthreads();
    for (int off = 1; off < 64; off <<= 1) {
        int w = (t >= off) ? s[t - off] : 0;
        __syncthreads();
        s[t] += w;
        __syncthreads();
    }
    bin_base[t] = s[t] - v;  // exclusive
}

// ---------------------------------------------------------------------------
// Scatter nodes into the degree-sorted permutation.
// ---------------------------------------------------------------------------
__global__ void perm_scatter(const int* __restrict__ nodeinfo,
                             const int* __restrict__ bin_rel,
                             const int* __restrict__ bin_base,
                             int* __restrict__ perm) {
    int n = blockIdx.x * 256 + threadIdx.x;
    if (n >= N_NODES) return;
    int b = n / DPB;
    int info = nodeinfo[n];
    int bin = info >> 9;
    int lpos = info & 511;
    perm[bin_base[bin] + bin_rel[b * 64 + bin] + lpos] = n;
}

// ---------------------------------------------------------------------------
// Pull aggregation v6: wave = 8 nodes taken through the DEGREE-SORTED perm
// (adjacent nodes have near-equal deg -> no masked-tail waste). Each 8-lane
// group owns one node; 4-deep software pipeline with statically-named regs;
// packed 4B rec (src:17 | u:15). Zero cross-lane shuffles.
// ---------------------------------------------------------------------------
__global__ __launch_bounds__(256) void pull_agg(
        const int* __restrict__ rowptr, const int* __restrict__ cnt,
        const int* __restrict__ perm, const unsigned* __restrict__ rec,
        const unsigned short* __restrict__ featb,
        unsigned short* __restrict__ s01b) {
    int gid = (blockIdx.x * 256 + threadIdx.x) >> 6;
    int lane = threadIdx.x & 63;
    int fg = lane & 7;    // 16B chunk (8 bf16) within the 128B row
    int eg = lane >> 3;   // node subgroup 0..7
    int idx = gid * 8 + eg;
    bool valid = idx < N_NODES;
    int n = 0, start = 0, deg = 0;
    if (valid) { n = perm[idx]; start = rowptr[n]; deg = cnt[n]; }
    int end = start + deg;
    int il  = end - 1;
    const bf16x8* f8 = reinterpret_cast<const bf16x8*>(featb);
    float s[8], a1[8];
#pragma unroll
    for (int k = 0; k < 8; ++k) { s[k] = 0.0f; a1[k] = 0.0f; }

#define LD(IDX, R, V)                                              \
    { int ic = min(IDX, il); R = rec[ic];                          \
      V = f8[((size_t)(R >> 15) << 3) + fg]; }
#define MATH(IDX, R, V)                                            \
    { float mk = (IDX < end) ? 1.0f : 0.0f;                        \
      float um = mk * (float)(R & 0x7FFFu) * (1.0f / 32768.0f);    \
      _Pragma("unroll")                                            \
      for (int t = 0; t < 8; ++t) {                                \
          float vv = bf2f((unsigned short)V[t]);                   \
          s[t]  = fmaf(mk, vv, s[t]);                              \
          a1[t] = fmaf(um, vv, a1[t]);                             \
      } }

    if (deg > 0) {
        int i = start;
        unsigned r0, r1, r2, r3; bf16x8 v0, v1, v2, v3;
        LD(i,     r0, v0)
        LD(i + 1, r1, v1)
        LD(i + 2, r2, v2)
        LD(i + 3, r3, v3)
        while (true) {
            int j = i + 4;
            bool more = j < end;
            unsigned q0, q1, q2, q3; bf16x8 w0, w1, w2, w3;
            if (more) {           // issue next batch's 4 gathers first
                LD(j,     q0, w0)
                LD(j + 1, q1, w1)
                LD(j + 2, q2, w2)
                LD(j + 3, q3, w3)
            }
            MATH(i,     r0, v0)
            MATH(i + 1, r1, v1)
            MATH(i + 2, r2, v2)
            MATH(i + 3, r3, v3)
            if (!more) break;
            i = j;
            r0 = q0; v0 = w0; r1 = q1; v1 = w1;
            r2 = q2; v2 = w2; r3 = q3; v3 = w3;
        }
    }
#undef LD
#undef MATH

    if (valid) {
        float dinv = 1.0f / fmaxf((float)deg, 1.0f);
        bf16x8 o0, o1;
#pragma unroll
        for (int k = 0; k < 8; ++k) {
            o0[k] = (short)f2bf((s[k] - a1[k]) * dinv);
            o1[k] = (short)f2bf(a1[k] * dinv);
        }
        *reinterpret_cast<bf16x8*>(s01b + (size_t)n * 128 + fg * 8) = o0;
        *reinterpret_cast<bf16x8*>(s01b + (size_t)n * 128 + 64 + fg * 8) = o1;
    }
}

// ---------------------------------------------------------------------------
// MFMA node transform (per block 256 nodes; wave owns 64). K=192 in 6 steps.
// D = Wt-frag x z-frag = C^T: lane holds node = base+(lane&15), channels
// ct*16 + (lane>>4)*4 + reg. ACT=1: ELU->bf16. ACT=2: log_softmax->f32.
// ---------------------------------------------------------------------------
template<int COUT, int CT, int ACT>
__global__ __launch_bounds__(256) void gemm_mfma(
        const unsigned short* __restrict__ s01b,
        const unsigned short* __restrict__ featb,
        const unsigned short* __restrict__ Wt,
        const float* __restrict__ bias, void* __restrict__ outv) {
    int lane = threadIdx.x & 63;
    int wave = threadIdx.x >> 6;
    int l15  = lane & 15;
    int g    = lane >> 4;
    int nodebase = blockIdx.x * 256 + wave * 64;

    f32x4 acc[4][CT];
#pragma unroll
    for (int rt = 0; rt < 4; ++rt)
#pragma unroll
        for (int ct = 0; ct < CT; ++ct) acc[rt][ct] = (f32x4){0.f, 0.f, 0.f, 0.f};

#pragma unroll
    for (int ks = 0; ks < 6; ++ks) {
        int kk = ks * 32 + g * 8;
        bf16x8 zfrag[4];
#pragma unroll
        for (int rt = 0; rt < 4; ++rt) {
            int n = nodebase + rt * 16 + l15;
            if (n >= N_NODES) n = N_NODES - 1;
            const unsigned short* p = (kk < 128)
                ? (s01b + (size_t)n * 128 + kk)
                : (featb + (size_t)n * 64 + (kk - 128));
            zfrag[rt] = *reinterpret_cast<const bf16x8*>(p);
        }
        bf16x8 wfrag[CT];
#pragma unroll
        for (int ct = 0; ct < CT; ++ct)
            wfrag[ct] = *reinterpret_cast<const bf16x8*>(Wt + (size_t)(ct * 16 + l15) * 192 + kk);
#pragma unroll
        for (int rt = 0; rt < 4; ++rt)
#pragma unroll
            for (int ct = 0; ct < CT; ++ct)
                acc[rt][ct] = __builtin_amdgcn_mfma_f32_16x16x32_bf16(
                    wfrag[ct], zfrag[rt], acc[rt][ct], 0, 0, 0);
    }

    f32x4 bv[CT];
#pragma unroll
    for (int ct = 0; ct < CT; ++ct) {
        int base = ct * 16 + g * 4;
        if (base + 4 <= COUT) {
            float4 b = *reinterpret_cast<const float4*>(bias + base);
            bv[ct] = (f32x4){b.x, b.y, b.z, b.w};
        } else {
            bv[ct] = (f32x4){0.f, 0.f, 0.f, 0.f};
        }
    }

    if (ACT == 1) {
        unsigned short* out = (unsigned short*)outv;
#pragma unroll
        for (int rt = 0; rt < 4; ++rt) {
            int n = nodebase + rt * 16 + l15;
            if (n >= N_NODES) continue;
#pragma unroll
            for (int ct = 0; ct < CT; ++ct) {
                f32x4 v = acc[rt][ct] + bv[ct];
                ushort4 o;
                float e;
                e = v[0]; o.x = f2bf(e > 0.f ? e : expm1f(e));
                e = v[1]; o.y = f2bf(e > 0.f ? e : expm1f(e));
                e = v[2]; o.z = f2bf(e > 0.f ? e : expm1f(e));
                e = v[3]; o.w = f2bf(e > 0.f ? e : expm1f(e));
                *reinterpret_cast<ushort4*>(out + (size_t)n * 64 + ct * 16 + g * 4) = o;
            }
        }
    } else {
        float* out = (float*)outv;
#pragma unroll
        for (int rt = 0; rt < 4; ++rt) {
            int n = nodebase + rt * 16 + l15;
            float v[CT * 4];
            float m = -3.4e38f;
#pragma unroll
            for (int ct = 0; ct < CT; ++ct)
#pragma unroll
                for (int r = 0; r < 4; ++r) {
                    int ch = ct * 16 + g * 4 + r;
                    float t = acc[rt][ct][r] + bv[ct][r];
                    v[ct * 4 + r] = t;
                    if (ch < COUT) m = fmaxf(m, t);
                }
            m = fmaxf(m, __shfl_xor(m, 16));
            m = fmaxf(m, __shfl_xor(m, 32));
            float s = 0.0f;
#pragma unroll
            for (int ct = 0; ct < CT; ++ct)
#pragma unroll
                for (int r = 0; r < 4; ++r) {
                    int ch = ct * 16 + g * 4 + r;
                    if (ch < COUT) s += expf(v[ct * 4 + r] - m);
                }
            s += __shfl_xor(s, 16);
            s += __shfl_xor(s, 32);
            float lse = m + logf(s);
            if (n >= N_NODES) continue;
#pragma unroll
            for (int ct = 0; ct < CT; ++ct) {
                int base = ct * 16 + g * 4;
                if (base + 4 <= COUT) {
                    float4 o;
                    o.x = v[ct * 4 + 0] - lse;
                    o.y = v[ct * 4 + 1] - lse;
                    o.z = v[ct * 4 + 2] - lse;
                    o.w = v[ct * 4 + 3] - lse;
                    *reinterpret_cast<float4*>(out + (size_t)n * COUT + base) = o;
                }
            }
        }
    }
}

extern "C" void kernel_launch(void* const* d_in, const int* in_sizes, int n_in,
                              void* d_out, int out_size, void* d_ws, size_t ws_size,
                              hipStream_t stream) {
    const float* x     = (const float*)d_in[0];
    const int*   ei    = (const int*)d_in[1];
    const float* ea    = (const float*)d_in[2];
    const float* W1    = (const float*)d_in[3];
    const float* root1 = (const float*)d_in[4];
    const float* b1    = (const float*)d_in[5];
    const float* W2    = (const float*)d_in[6];
    const float* root2 = (const float*)d_in[7];
    const float* b2    = (const float*)d_in[8];
    float* out = (float*)d_out;

    // workspace layout
    char* p = (char*)d_ws;
    int*   bucket_cur = (int*)p;            p += 512 * 4;
    int*   bin_cnt  = (int*)p;              p += 64 * 4;
    int*   bin_base = (int*)p;              p += 64 * 4;
    int*   bin_rel  = (int*)p;              p += (size_t)NBUK * 64 * 4;
    int*   nodeinfo = (int*)p;              p += (size_t)N_NODES * 4;
    int*   perm     = (int*)p;              p += (size_t)N_NODES * 4;
    int2*  binned  = (int2*)p;              p += (size_t)NBUK * BSTRIDE * 8;
    unsigned* rec  = (unsigned*)p;          p += (size_t)N_EDGES * 4;
    int*   rowptr  = (int*)p;               p += (size_t)N_NODES * 4;
    int*   cnt     = (int*)p;               p += (size_t)N_NODES * 4;
    unsigned short* s01b = (unsigned short*)p;  p += (size_t)N_NODES * 128 * 2;
    unsigned short* xb   = (unsigned short*)p;  p += (size_t)N_NODES * 64 * 2;
    unsigned short* hprb = (unsigned short*)p;  p += (size_t)N_NODES * 64 * 2;
    unsigned short* Wt1  = (unsigned short*)p;  p += (size_t)64 * 192 * 2;
    unsigned short* Wt2  = (unsigned short*)p;  p += (size_t)48 * 192 * 2;

    // ---- prep ----
    x2bf16_kernel<<<(N_NODES * 16) / 256, 256, 0, stream>>>(x, xb);
    wt_kernel<<<48, 256, 0, stream>>>(W1, root1, Wt1, 64, 64 * 192);
    wt_kernel<<<36, 256, 0, stream>>>(W2, root2, Wt2, 40, 48 * 192);
    hipMemsetAsync(bucket_cur, 0, (512 + 64) * 4, stream);  // bucket_cur + bin_cnt

    // ---- CSR build: 2-phase counting sort, key = (dst, src_tile) ----
    bin_edges<<<NCHA, 256, 0, stream>>>(ei, ea, bucket_cur, binned);
    bucket_sort<<<NBUK, 512, 0, stream>>>(bucket_cur, binned, rec, rowptr, cnt,
                                          bin_cnt, bin_rel, nodeinfo);
    scan64<<<1, 64, 0, stream>>>(bin_cnt, bin_base);
    perm_scatter<<<NB_SCAN, 256, 0, stream>>>(nodeinfo, bin_rel, bin_base, perm);

    // ---- layer 1 ----  (wave = 8 nodes -> 3125 blocks)
    pull_agg<<<(N_NODES + 31) / 32, 256, 0, stream>>>(rowptr, cnt, perm, rec, xb, s01b);
    gemm_mfma<64, 4, 1><<<NB_SCAN, 256, 0, stream>>>(s01b, xb, Wt1, b1, hprb);

    // ---- layer 2 ----
    pull_agg<<<(N_NODES + 31) / 32, 256, 0, stream>>>(rowptr, cnt, perm, rec, hprb, s01b);
    gemm_mfma<40, 3, 2><<<NB_SCAN, 256, 0, stream>>>(s01b, hprb, Wt2, b2, out);
}

// Round 13
// 160.689 us; speedup vs baseline: 1.0502x; 1.0502x over previous
//
#include <hip/hip_runtime.h>
#include <math.h>

#define N_NODES 100000
#define N_EDGES 1600000
#define NB_SCAN 391   // ceil(N_NODES/256)
#define CHUNK 4096
#define NCHA 391      // ceil(N_EDGES/CHUNK)
#define NBUK 256      // coarse dst buckets
#define DPB 391       // dsts per bucket (256*391 = 100096 >= 100000)
#define BSTRIDE 7168  // per-bucket capacity (mean 6250, sigma ~79)
#define TILE_N 25000  // src tile (3.2 MB bf16, fits 4 MB XCD L2)

typedef __attribute__((ext_vector_type(8))) short bf16x8;
typedef __attribute__((ext_vector_type(4))) float f32x4;

__device__ __forceinline__ unsigned short f2bf(float f) {
    union { float f; unsigned u; } v; v.f = f;
    unsigned r = v.u + 0x7FFF + ((v.u >> 16) & 1);  // round-nearest-even
    return (unsigned short)(r >> 16);
}
__device__ __forceinline__ float bf2f(unsigned short b) {
    union { unsigned u; float f; } v; v.u = ((unsigned)b) << 16;
    return v.f;
}

// ---------------------------------------------------------------------------
// f32 -> bf16 row copy of x (for the gather path).
// ---------------------------------------------------------------------------
__global__ void x2bf16_kernel(const float* __restrict__ x,
                              unsigned short* __restrict__ xb) {
    int i = blockIdx.x * 256 + threadIdx.x;
    if (i >= N_NODES * 16) return;
    float4 v = reinterpret_cast<const float4*>(x)[i];
    ushort4 o;
    o.x = f2bf(v.x); o.y = f2bf(v.y); o.z = f2bf(v.z); o.w = f2bf(v.w);
    reinterpret_cast<ushort4*>(xb)[i] = o;
}

// ---------------------------------------------------------------------------
// Weight transpose+cast: Wt[c][k] = {W[0],W[1],root}[k][c], bf16; pad rows 0.
// ---------------------------------------------------------------------------
__global__ void wt_kernel(const float* __restrict__ W, const float* __restrict__ root,
                          unsigned short* __restrict__ Wt, int COUT, int total) {
    int i = blockIdx.x * 256 + threadIdx.x;
    if (i >= total) return;
    int c = i / 192;
    int k = i - c * 192;
    float v = 0.0f;
    if (c < COUT)
        v = (k < 128) ? W[(k >> 6) * 64 * COUT + (k & 63) * COUT + c]
                      : root[(k - 128) * COUT + c];
    Wt[i] = f2bf(v);
}

// ---------------------------------------------------------------------------
// Phase A: bin edges into 256 coarse dst-buckets with LDS compaction, so all
// global writes are contiguous runs. Record: {src, u16<<16 | dst_local(10b)}.
// ---------------------------------------------------------------------------
__global__ __launch_bounds__(256) void bin_edges(const int* __restrict__ ei,
                                                 const float* __restrict__ ea,
                                                 int* __restrict__ bucket_cur,
                                                 int2* __restrict__ binned) {
    __shared__ int hist[NBUK];
    __shared__ int lbase[NBUK];
    __shared__ int lcur[NBUK];
    __shared__ int gbase[NBUK];
    __shared__ int2 stage[CHUNK];
    __shared__ unsigned char sbkt[CHUNK];
    int tid = threadIdx.x;
    int e0 = blockIdx.x * CHUNK;
    int nval = min(CHUNK, N_EDGES - e0);

    if (tid < NBUK) hist[tid] = 0;
    __syncthreads();
    for (int j = tid; j < nval; j += 256)
        atomicAdd(&hist[ei[N_EDGES + e0 + j] / DPB], 1);
    __syncthreads();
    if (tid < NBUK) lbase[tid] = hist[tid];
    __syncthreads();
    for (int off = 1; off < NBUK; off <<= 1) {
        int v = (tid < NBUK && tid >= off) ? lbase[tid - off] : 0;
        __syncthreads();
        if (tid < NBUK) lbase[tid] += v;
        __syncthreads();
    }
    if (tid < NBUK) {
        int ex = lbase[tid] - hist[tid];  // exclusive
        lbase[tid] = ex;
        lcur[tid]  = ex;
        gbase[tid] = atomicAdd(&bucket_cur[tid], hist[tid]);
    }
    __syncthreads();
    for (int j = tid; j < nval; j += 256) {
        int e = e0 + j;
        int d = ei[N_EDGES + e];
        int b = d / DPB;
        int dl = d - b * DPB;
        float u = ea[e];
        int uq = min((int)(u * 65536.0f + 0.5f), 65535);
        int pos = atomicAdd(&lcur[b], 1);
        stage[pos] = make_int2(ei[e], (uq << 16) | dl);
        sbkt[pos] = (unsigned char)b;
    }
    __syncthreads();
    for (int j = tid; j < nval; j += 256) {
        int b = sbkt[j];
        int gp = gbase[b] + (j - lbase[b]);
        if (gp < BSTRIDE)
            binned[(size_t)b * BSTRIDE + gp] = stage[j];
    }
}

// ---------------------------------------------------------------------------
// Phase B: per-bucket counting sort over key = dst_local*4 + src_tile.
// Emits rowptr[d], cnt[d], and packed 4B rec = (src<<15 | u15); per-node
// record lists are src-tile-ordered for L2 phase coherence in the pull.
// ---------------------------------------------------------------------------
__global__ __launch_bounds__(512) void bucket_sort(const int* __restrict__ bucket_cur,
                                                   const int2* __restrict__ binned,
                                                   unsigned* __restrict__ rec,
                                                   int* __restrict__ rowptr,
                                                   int* __restrict__ cnt_g) {
    __shared__ int keycnt[1600];
    __shared__ int tsum[512];
    __shared__ unsigned stage[BSTRIDE];
    int tid = threadIdx.x;
    int b = blockIdx.x;

    // global base of this bucket = exclusive prefix of bucket sizes
    tsum[tid] = (tid < NBUK) ? bucket_cur[tid] : 0;
    __syncthreads();
    for (int off = 1; off < 512; off <<= 1) {
        int v = (tid >= off) ? tsum[tid - off] : 0;
        __syncthreads();
        tsum[tid] += v;
        __syncthreads();
    }
    int base = (b == 0) ? 0 : tsum[b - 1];
    int m = min(bucket_cur[b], BSTRIDE);
    __syncthreads();

    for (int k = tid; k < 1600; k += 512) keycnt[k] = 0;
    __syncthreads();
    const int2* bin = binned + (size_t)b * BSTRIDE;
    for (int j = tid; j < m; j += 512) {
        int2 r = bin[j];
        int key = ((r.y & 1023) << 2) | ((unsigned)r.x / TILE_N);
        atomicAdd(&keycnt[key], 1);
    }
    __syncthreads();
    int k0 = tid << 2;
    int c0 = 0, c1 = 0, c2 = 0, c3 = 0;
    if (tid < DPB) {
        c0 = keycnt[k0]; c1 = keycnt[k0 + 1];
        c2 = keycnt[k0 + 2]; c3 = keycnt[k0 + 3];
    }
    int s4 = c0 + c1 + c2 + c3;
    tsum[tid] = s4;
    __syncthreads();
    for (int off = 1; off < 512; off <<= 1) {
        int v = (tid >= off) ? tsum[tid - off] : 0;
        __syncthreads();
        tsum[tid] += v;
        __syncthreads();
    }
    if (tid < DPB) {
        int p = tsum[tid] - s4;  // exclusive over keys
        int d = b * DPB + tid;
        if (d < N_NODES) {
            rowptr[d] = base + p;
            cnt_g[d]  = s4;
        }
        keycnt[k0] = p;     p += c0;
        keycnt[k0 + 1] = p; p += c1;
        keycnt[k0 + 2] = p; p += c2;
        keycnt[k0 + 3] = p;
    }
    __syncthreads();
    for (int j = tid; j < m; j += 512) {
        int2 r = bin[j];
        int key = ((r.y & 1023) << 2) | ((unsigned)r.x / TILE_N);
        unsigned uq15 = ((unsigned)r.y >> 17);  // 15-bit u
        int pos = atomicAdd(&keycnt[key], 1);
        if (pos < BSTRIDE) stage[pos] = ((unsigned)r.x << 15) | uq15;
    }
    __syncthreads();
    for (int j = tid; j < m; j += 512)
        rec[base + j] = stage[j];
}

// ---------------------------------------------------------------------------
// Pull aggregation v7: wave = 8 CONSECUTIVE nodes (natural dst order keeps
// rec segments adjacent and s01b writes block-coalesced). Each 8-lane group
// owns one node; 4-deep software pipeline with statically-named regs; packed
// 4B rec (src:17 | u:15). Zero cross-lane shuffles.
// ---------------------------------------------------------------------------
__global__ __launch_bounds__(256) void pull_agg(
        const int* __restrict__ rowptr, const int* __restrict__ cnt,
        const unsigned* __restrict__ rec,
        const unsigned short* __restrict__ featb,
        unsigned short* __restrict__ s01b) {
    int gid = (blockIdx.x * 256 + threadIdx.x) >> 6;
    int lane = threadIdx.x & 63;
    int fg = lane & 7;    // 16B chunk (8 bf16) within the 128B row
    int eg = lane >> 3;   // node subgroup 0..7
    int n = gid * 8 + eg;
    bool valid = n < N_NODES;
    int start = 0, deg = 0;
    if (valid) { start = rowptr[n]; deg = cnt[n]; }
    int end = start + deg;
    int il  = end - 1;
    const bf16x8* f8 = reinterpret_cast<const bf16x8*>(featb);
    float s[8], a1[8];
#pragma unroll
    for (int k = 0; k < 8; ++k) { s[k] = 0.0f; a1[k] = 0.0f; }

#define LD(IDX, R, V)                                              \
    { int ic = min(IDX, il); R = rec[ic];                          \
      V = f8[((size_t)(R >> 15) << 3) + fg]; }
#define MATH(IDX, R, V)                                            \
    { float mk = (IDX < end) ? 1.0f : 0.0f;                        \
      float um = mk * (float)(R & 0x7FFFu) * (1.0f / 32768.0f);    \
      _Pragma("unroll")                                            \
      for (int t = 0; t < 8; ++t) {                                \
          float vv = bf2f((unsigned short)V[t]);                   \
          s[t]  = fmaf(mk, vv, s[t]);                              \
          a1[t] = fmaf(um, vv, a1[t]);                             \
      } }

    if (deg > 0) {
        int i = start;
        unsigned r0, r1, r2, r3; bf16x8 v0, v1, v2, v3;
        LD(i,     r0, v0)
        LD(i + 1, r1, v1)
        LD(i + 2, r2, v2)
        LD(i + 3, r3, v3)
        while (true) {
            int j = i + 4;
            bool more = j < end;
            unsigned q0, q1, q2, q3; bf16x8 w0, w1, w2, w3;
            if (more) {           // issue next batch's 4 gathers first
                LD(j,     q0, w0)
                LD(j + 1, q1, w1)
                LD(j + 2, q2, w2)
                LD(j + 3, q3, w3)
            }
            MATH(i,     r0, v0)
            MATH(i + 1, r1, v1)
            MATH(i + 2, r2, v2)
            MATH(i + 3, r3, v3)
            if (!more) break;
            i = j;
            r0 = q0; v0 = w0; r1 = q1; v1 = w1;
            r2 = q2; v2 = w2; r3 = q3; v3 = w3;
        }
    }
#undef LD
#undef MATH

    if (valid) {
        float dinv = 1.0f / fmaxf((float)deg, 1.0f);
        bf16x8 o0, o1;
#pragma unroll
        for (int k = 0; k < 8; ++k) {
            o0[k] = (short)f2bf((s[k] - a1[k]) * dinv);
            o1[k] = (short)f2bf(a1[k] * dinv);
        }
        *reinterpret_cast<bf16x8*>(s01b + (size_t)n * 128 + fg * 8) = o0;
        *reinterpret_cast<bf16x8*>(s01b + (size_t)n * 128 + 64 + fg * 8) = o1;
    }
}

// ---------------------------------------------------------------------------
// MFMA node transform (per block 256 nodes; wave owns 64). K=192 in 6 steps.
// D = Wt-frag x z-frag = C^T: lane holds node = base+(lane&15), channels
// ct*16 + (lane>>4)*4 + reg. ACT=1: ELU->bf16. ACT=2: log_softmax->f32.
// ---------------------------------------------------------------------------
template<int COUT, int CT, int ACT>
__global__ __launch_bounds__(256) void gemm_mfma(
        const unsigned short* __restrict__ s01b,
        const unsigned short* __restrict__ featb,
        const unsigned short* __restrict__ Wt,
        const float* __restrict__ bias, void* __restrict__ outv) {
    int lane = threadIdx.x & 63;
    int wave = threadIdx.x >> 6;
    int l15  = lane & 15;
    int g    = lane >> 4;
    int nodebase = blockIdx.x * 256 + wave * 64;

    f32x4 acc[4][CT];
#pragma unroll
    for (int rt = 0; rt < 4; ++rt)
#pragma unroll
        for (int ct = 0; ct < CT; ++ct) acc[rt][ct] = (f32x4){0.f, 0.f, 0.f, 0.f};

#pragma unroll
    for (int ks = 0; ks < 6; ++ks) {
        int kk = ks * 32 + g * 8;
        bf16x8 zfrag[4];
#pragma unroll
        for (int rt = 0; rt < 4; ++rt) {
            int n = nodebase + rt * 16 + l15;
            if (n >= N_NODES) n = N_NODES - 1;
            const unsigned short* p = (kk < 128)
                ? (s01b + (size_t)n * 128 + kk)
                : (featb + (size_t)n * 64 + (kk - 128));
            zfrag[rt] = *reinterpret_cast<const bf16x8*>(p);
        }
        bf16x8 wfrag[CT];
#pragma unroll
        for (int ct = 0; ct < CT; ++ct)
            wfrag[ct] = *reinterpret_cast<const bf16x8*>(Wt + (size_t)(ct * 16 + l15) * 192 + kk);
#pragma unroll
        for (int rt = 0; rt < 4; ++rt)
#pragma unroll
            for (int ct = 0; ct < CT; ++ct)
                acc[rt][ct] = __builtin_amdgcn_mfma_f32_16x16x32_bf16(
                    wfrag[ct], zfrag[rt], acc[rt][ct], 0, 0, 0);
    }

    f32x4 bv[CT];
#pragma unroll
    for (int ct = 0; ct < CT; ++ct) {
        int base = ct * 16 + g * 4;
        if (base + 4 <= COUT) {
            float4 b = *reinterpret_cast<const float4*>(bias + base);
            bv[ct] = (f32x4){b.x, b.y, b.z, b.w};
        } else {
            bv[ct] = (f32x4){0.f, 0.f, 0.f, 0.f};
        }
    }

    if (ACT == 1) {
        unsigned short* out = (unsigned short*)outv;
#pragma unroll
        for (int rt = 0; rt < 4; ++rt) {
            int n = nodebase + rt * 16 + l15;
            if (n >= N_NODES) continue;
#pragma unroll
            for (int ct = 0; ct < CT; ++ct) {
                f32x4 v = acc[rt][ct] + bv[ct];
                ushort4 o;
                float e;
                e = v[0]; o.x = f2bf(e > 0.f ? e : expm1f(e));
                e = v[1]; o.y = f2bf(e > 0.f ? e : expm1f(e));
                e = v[2]; o.z = f2bf(e > 0.f ? e : expm1f(e));
                e = v[3]; o.w = f2bf(e > 0.f ? e : expm1f(e));
                *reinterpret_cast<ushort4*>(out + (size_t)n * 64 + ct * 16 + g * 4) = o;
            }
        }
    } else {
        float* out = (float*)outv;
#pragma unroll
        for (int rt = 0; rt < 4; ++rt) {
            int n = nodebase + rt * 16 + l15;
            float v[CT * 4];
            float m = -3.4e38f;
#pragma unroll
            for (int ct = 0; ct < CT; ++ct)
#pragma unroll
                for (int r = 0; r < 4; ++r) {
                    int ch = ct * 16 + g * 4 + r;
                    float t = acc[rt][ct][r] + bv[ct][r];
                    v[ct * 4 + r] = t;
                    if (ch < COUT) m = fmaxf(m, t);
                }
            m = fmaxf(m, __shfl_xor(m, 16));
            m = fmaxf(m, __shfl_xor(m, 32));
            float s = 0.0f;
#pragma unroll
            for (int ct = 0; ct < CT; ++ct)
#pragma unroll
                for (int r = 0; r < 4; ++r) {
                    int ch = ct * 16 + g * 4 + r;
                    if (ch < COUT) s += expf(v[ct * 4 + r] - m);
                }
            s += __shfl_xor(s, 16);
            s += __shfl_xor(s, 32);
            float lse = m + logf(s);
            if (n >= N_NODES) continue;
#pragma unroll
            for (int ct = 0; ct < CT; ++ct) {
                int base = ct * 16 + g * 4;
                if (base + 4 <= COUT) {
                    float4 o;
                    o.x = v[ct * 4 + 0] - lse;
                    o.y = v[ct * 4 + 1] - lse;
                    o.z = v[ct * 4 + 2] - lse;
                    o.w = v[ct * 4 + 3] - lse;
                    *reinterpret_cast<float4*>(out + (size_t)n * COUT + base) = o;
                }
            }
        }
    }
}

extern "C" void kernel_launch(void* const* d_in, const int* in_sizes, int n_in,
                              void* d_out, int out_size, void* d_ws, size_t ws_size,
                              hipStream_t stream) {
    const float* x     = (const float*)d_in[0];
    const int*   ei    = (const int*)d_in[1];
    const float* ea    = (const float*)d_in[2];
    const float* W1    = (const float*)d_in[3];
    const float* root1 = (const float*)d_in[4];
    const float* b1    = (const float*)d_in[5];
    const float* W2    = (const float*)d_in[6];
    const float* root2 = (const float*)d_in[7];
    const float* b2    = (const float*)d_in[8];
    float* out = (float*)d_out;

    // workspace layout
    char* p = (char*)d_ws;
    int*   bucket_cur = (int*)p;            p += 512 * 4;
    int2*  binned  = (int2*)p;              p += (size_t)NBUK * BSTRIDE * 8;
    unsigned* rec  = (unsigned*)p;          p += (size_t)N_EDGES * 4;
    int*   rowptr  = (int*)p;               p += (size_t)N_NODES * 4;
    int*   cnt     = (int*)p;               p += (size_t)N_NODES * 4;
    unsigned short* s01b = (unsigned short*)p;  p += (size_t)N_NODES * 128 * 2;
    unsigned short* xb   = (unsigned short*)p;  p += (size_t)N_NODES * 64 * 2;
    unsigned short* hprb = (unsigned short*)p;  p += (size_t)N_NODES * 64 * 2;
    unsigned short* Wt1  = (unsigned short*)p;  p += (size_t)64 * 192 * 2;
    unsigned short* Wt2  = (unsigned short*)p;  p += (size_t)48 * 192 * 2;

    // ---- prep ----
    x2bf16_kernel<<<(N_NODES * 16) / 256, 256, 0, stream>>>(x, xb);
    wt_kernel<<<48, 256, 0, stream>>>(W1, root1, Wt1, 64, 64 * 192);
    wt_kernel<<<36, 256, 0, stream>>>(W2, root2, Wt2, 40, 48 * 192);
    hipMemsetAsync(bucket_cur, 0, 512 * 4, stream);

    // ---- CSR build: 2-phase counting sort, key = (dst, src_tile) ----
    bin_edges<<<NCHA, 256, 0, stream>>>(ei, ea, bucket_cur, binned);
    bucket_sort<<<NBUK, 512, 0, stream>>>(bucket_cur, binned, rec, rowptr, cnt);

    // ---- layer 1 ----  (wave = 8 nodes -> 3125 blocks)
    pull_agg<<<(N_NODES + 31) / 32, 256, 0, stream>>>(rowptr, cnt, rec, xb, s01b);
    gemm_mfma<64, 4, 1><<<NB_SCAN, 256, 0, stream>>>(s01b, xb, Wt1, b1, hprb);

    // ---- layer 2 ----
    pull_agg<<<(N_NODES + 31) / 32, 256, 0, stream>>>(rowptr, cnt, rec, hprb, s01b);
    gemm_mfma<40, 3, 2><<<NB_SCAN, 256, 0, stream>>>(s01b, hprb, Wt2, b2, out);
}

// Round 14
// 157.415 us; speedup vs baseline: 1.0720x; 1.0208x over previous
//
#include <hip/hip_runtime.h>
#include <math.h>

#define N_NODES 100000
#define N_EDGES 1600000
#define NB_SCAN 391   // ceil(N_NODES/256)
#define CHUNK 4096
#define NCHA 391      // ceil(N_EDGES/CHUNK)
#define NBUK 256      // coarse dst buckets
#define DPB 391       // dsts per bucket (256*391 = 100096 >= 100000)
#define BSTRIDE 7168  // per-bucket capacity (mean 6250, sigma ~79)
#define TILE_N 12500  // src tile (1.6 MB bf16; 8 tiles, L2-resident w/ headroom)
#define NKEY 3200     // DPB*8 = 3128, rounded up

typedef __attribute__((ext_vector_type(8))) short bf16x8;
typedef __attribute__((ext_vector_type(4))) float f32x4;

__device__ __forceinline__ unsigned short f2bf(float f) {
    union { float f; unsigned u; } v; v.f = f;
    unsigned r = v.u + 0x7FFF + ((v.u >> 16) & 1);  // round-nearest-even
    return (unsigned short)(r >> 16);
}
__device__ __forceinline__ float bf2f(unsigned short b) {
    union { unsigned u; float f; } v; v.u = ((unsigned)b) << 16;
    return v.f;
}

// ---------------------------------------------------------------------------
// f32 -> bf16 row copy of x (for the gather path).
// ---------------------------------------------------------------------------
__global__ void x2bf16_kernel(const float* __restrict__ x,
                              unsigned short* __restrict__ xb) {
    int i = blockIdx.x * 256 + threadIdx.x;
    if (i >= N_NODES * 16) return;
    float4 v = reinterpret_cast<const float4*>(x)[i];
    ushort4 o;
    o.x = f2bf(v.x); o.y = f2bf(v.y); o.z = f2bf(v.z); o.w = f2bf(v.w);
    reinterpret_cast<ushort4*>(xb)[i] = o;
}

// ---------------------------------------------------------------------------
// Weight transpose+cast for BOTH layers in one launch:
// blocks [0,48): Wt1[c][k] from W1/root1 (COUT=64);
// blocks [48,84): Wt2[c][k] from W2/root2 (COUT=40, padded to 48 rows).
// ---------------------------------------------------------------------------
__global__ void wt_all(const float* __restrict__ W1, const float* __restrict__ root1,
                       const float* __restrict__ W2, const float* __restrict__ root2,
                       unsigned short* __restrict__ Wt1, unsigned short* __restrict__ Wt2) {
    int b = blockIdx.x;
    const float* W; const float* root; unsigned short* Wt; int COUT, i;
    if (b < 48) { W = W1; root = root1; Wt = Wt1; COUT = 64; i = b * 256 + threadIdx.x; }
    else        { W = W2; root = root2; Wt = Wt2; COUT = 40; i = (b - 48) * 256 + threadIdx.x; }
    int c = i / 192;
    int k = i - c * 192;
    float v = 0.0f;
    if (c < COUT)
        v = (k < 128) ? W[(k >> 6) * 64 * COUT + (k & 63) * COUT + c]
                      : root[(k - 128) * COUT + c];
    Wt[i] = f2bf(v);
}

// ---------------------------------------------------------------------------
// Phase A: bin edges into 256 coarse dst-buckets with LDS compaction, so all
// global writes are contiguous runs. Record: {src, u16<<16 | dst_local(10b)}.
// ---------------------------------------------------------------------------
__global__ __launch_bounds__(256) void bin_edges(const int* __restrict__ ei,
                                                 const float* __restrict__ ea,
                                                 int* __restrict__ bucket_cur,
                                                 int2* __restrict__ binned) {
    __shared__ int hist[NBUK];
    __shared__ int lbase[NBUK];
    __shared__ int lcur[NBUK];
    __shared__ int gbase[NBUK];
    __shared__ int2 stage[CHUNK];
    __shared__ unsigned char sbkt[CHUNK];
    int tid = threadIdx.x;
    int e0 = blockIdx.x * CHUNK;
    int nval = min(CHUNK, N_EDGES - e0);

    if (tid < NBUK) hist[tid] = 0;
    __syncthreads();
    for (int j = tid; j < nval; j += 256)
        atomicAdd(&hist[ei[N_EDGES + e0 + j] / DPB], 1);
    __syncthreads();
    if (tid < NBUK) lbase[tid] = hist[tid];
    __syncthreads();
    for (int off = 1; off < NBUK; off <<= 1) {
        int v = (tid < NBUK && tid >= off) ? lbase[tid - off] : 0;
        __syncthreads();
        if (tid < NBUK) lbase[tid] += v;
        __syncthreads();
    }
    if (tid < NBUK) {
        int ex = lbase[tid] - hist[tid];  // exclusive
        lbase[tid] = ex;
        lcur[tid]  = ex;
        gbase[tid] = atomicAdd(&bucket_cur[tid], hist[tid]);
    }
    __syncthreads();
    for (int j = tid; j < nval; j += 256) {
        int e = e0 + j;
        int d = ei[N_EDGES + e];
        int b = d / DPB;
        int dl = d - b * DPB;
        float u = ea[e];
        int uq = min((int)(u * 65536.0f + 0.5f), 65535);
        int pos = atomicAdd(&lcur[b], 1);
        stage[pos] = make_int2(ei[e], (uq << 16) | dl);
        sbkt[pos] = (unsigned char)b;
    }
    __syncthreads();
    for (int j = tid; j < nval; j += 256) {
        int b = sbkt[j];
        int gp = gbase[b] + (j - lbase[b]);
        if (gp < BSTRIDE)
            binned[(size_t)b * BSTRIDE + gp] = stage[j];
    }
}

// ---------------------------------------------------------------------------
// Phase B: per-bucket counting sort over key = dst_local*8 + src_tile(8).
// Emits rowptr[d], cnt[d], and packed 4B rec = (src<<15 | u15); per-node
// record lists are src-tile-ordered (8 tiles of 1.6 MB) for L2 coherence.
// ---------------------------------------------------------------------------
__global__ __launch_bounds__(512) void bucket_sort(const int* __restrict__ bucket_cur,
                                                   const int2* __restrict__ binned,
                                                   unsigned* __restrict__ rec,
                                                   int* __restrict__ rowptr,
                                                   int* __restrict__ cnt_g) {
    __shared__ int keycnt[NKEY];
    __shared__ int tsum[512];
    __shared__ unsigned stage[BSTRIDE];
    int tid = threadIdx.x;
    int b = blockIdx.x;

    // global base of this bucket = exclusive prefix of bucket sizes
    tsum[tid] = (tid < NBUK) ? bucket_cur[tid] : 0;
    __syncthreads();
    for (int off = 1; off < 512; off <<= 1) {
        int v = (tid >= off) ? tsum[tid - off] : 0;
        __syncthreads();
        tsum[tid] += v;
        __syncthreads();
    }
    int base = (b == 0) ? 0 : tsum[b - 1];
    int m = min(bucket_cur[b], BSTRIDE);
    __syncthreads();

    for (int k = tid; k < NKEY; k += 512) keycnt[k] = 0;
    __syncthreads();
    const int2* bin = binned + (size_t)b * BSTRIDE;
    for (int j = tid; j < m; j += 512) {
        int2 r = bin[j];
        int key = ((r.y & 1023) << 3) | ((unsigned)r.x / TILE_N);
        atomicAdd(&keycnt[key], 1);
    }
    __syncthreads();
    int k0 = tid << 3;
    int c[8];
    int s8 = 0;
    if (tid < DPB) {
#pragma unroll
        for (int t = 0; t < 8; ++t) { c[t] = keycnt[k0 + t]; s8 += c[t]; }
    }
    tsum[tid] = s8;
    __syncthreads();
    for (int off = 1; off < 512; off <<= 1) {
        int v = (tid >= off) ? tsum[tid - off] : 0;
        __syncthreads();
        tsum[tid] += v;
        __syncthreads();
    }
    if (tid < DPB) {
        int p = tsum[tid] - s8;  // exclusive over keys
        int d = b * DPB + tid;
        if (d < N_NODES) {
            rowptr[d] = base + p;
            cnt_g[d]  = s8;
        }
#pragma unroll
        for (int t = 0; t < 8; ++t) { keycnt[k0 + t] = p; p += c[t]; }
    }
    __syncthreads();
    for (int j = tid; j < m; j += 512) {
        int2 r = bin[j];
        int key = ((r.y & 1023) << 3) | ((unsigned)r.x / TILE_N);
        unsigned uq15 = ((unsigned)r.y >> 17);  // 15-bit u
        int pos = atomicAdd(&keycnt[key], 1);
        if (pos < BSTRIDE) stage[pos] = ((unsigned)r.x << 15) | uq15;
    }
    __syncthreads();
    for (int j = tid; j < m; j += 512)
        rec[base + j] = stage[j];
}

// ---------------------------------------------------------------------------
// Pull aggregation v7: wave = 8 CONSECUTIVE nodes (natural dst order keeps
// rec segments adjacent and s01b writes block-coalesced). Each 8-lane group
// owns one node; 4-deep software pipeline with statically-named regs; packed
// 4B rec (src:17 | u:15). Zero cross-lane shuffles.
// ---------------------------------------------------------------------------
__global__ __launch_bounds__(256) void pull_agg(
        const int* __restrict__ rowptr, const int* __restrict__ cnt,
        const unsigned* __restrict__ rec,
        const unsigned short* __restrict__ featb,
        unsigned short* __restrict__ s01b) {
    int gid = (blockIdx.x * 256 + threadIdx.x) >> 6;
    int lane = threadIdx.x & 63;
    int fg = lane & 7;    // 16B chunk (8 bf16) within the 128B row
    int eg = lane >> 3;   // node subgroup 0..7
    int n = gid * 8 + eg;
    bool valid = n < N_NODES;
    int start = 0, deg = 0;
    if (valid) { start = rowptr[n]; deg = cnt[n]; }
    int end = start + deg;
    int il  = end - 1;
    const bf16x8* f8 = reinterpret_cast<const bf16x8*>(featb);
    float s[8], a1[8];
#pragma unroll
    for (int k = 0; k < 8; ++k) { s[k] = 0.0f; a1[k] = 0.0f; }

#define LD(IDX, R, V)                                              \
    { int ic = min(IDX, il); R = rec[ic];                          \
      V = f8[((size_t)(R >> 15) << 3) + fg]; }
#define MATH(IDX, R, V)                                            \
    { float mk = (IDX < end) ? 1.0f : 0.0f;                        \
      float um = mk * (float)(R & 0x7FFFu) * (1.0f / 32768.0f);    \
      _Pragma("unroll")                                            \
      for (int t = 0; t < 8; ++t) {                                \
          float vv = bf2f((unsigned short)V[t]);                   \
          s[t]  = fmaf(mk, vv, s[t]);                              \
          a1[t] = fmaf(um, vv, a1[t]);                             \
      } }

    if (deg > 0) {
        int i = start;
        unsigned r0, r1, r2, r3; bf16x8 v0, v1, v2, v3;
        LD(i,     r0, v0)
        LD(i + 1, r1, v1)
        LD(i + 2, r2, v2)
        LD(i + 3, r3, v3)
        while (true) {
            int j = i + 4;
            bool more = j < end;
            unsigned q0, q1, q2, q3; bf16x8 w0, w1, w2, w3;
            if (more) {           // issue next batch's 4 gathers first
                LD(j,     q0, w0)
                LD(j + 1, q1, w1)
                LD(j + 2, q2, w2)
                LD(j + 3, q3, w3)
            }
            MATH(i,     r0, v0)
            MATH(i + 1, r1, v1)
            MATH(i + 2, r2, v2)
            MATH(i + 3, r3, v3)
            if (!more) break;
            i = j;
            r0 = q0; v0 = w0; r1 = q1; v1 = w1;
            r2 = q2; v2 = w2; r3 = q3; v3 = w3;
        }
    }
#undef LD
#undef MATH

    if (valid) {
        float dinv = 1.0f / fmaxf((float)deg, 1.0f);
        bf16x8 o0, o1;
#pragma unroll
        for (int k = 0; k < 8; ++k) {
            o0[k] = (short)f2bf((s[k] - a1[k]) * dinv);
            o1[k] = (short)f2bf(a1[k] * dinv);
        }
        *reinterpret_cast<bf16x8*>(s01b + (size_t)n * 128 + fg * 8) = o0;
        *reinterpret_cast<bf16x8*>(s01b + (size_t)n * 128 + 64 + fg * 8) = o1;
    }
}

// ---------------------------------------------------------------------------
// MFMA node transform (per block 256 nodes; wave owns 64). K=192 in 6 steps.
// D = Wt-frag x z-frag = C^T: lane holds node = base+(lane&15), channels
// ct*16 + (lane>>4)*4 + reg. ACT=1: ELU->bf16. ACT=2: log_softmax->f32.
// ---------------------------------------------------------------------------
template<int COUT, int CT, int ACT>
__global__ __launch_bounds__(256) void gemm_mfma(
        const unsigned short* __restrict__ s01b,
        const unsigned short* __restrict__ featb,
        const unsigned short* __restrict__ Wt,
        const float* __restrict__ bias, void* __restrict__ outv) {
    int lane = threadIdx.x & 63;
    int wave = threadIdx.x >> 6;
    int l15  = lane & 15;
    int g    = lane >> 4;
    int nodebase = blockIdx.x * 256 + wave * 64;

    f32x4 acc[4][CT];
#pragma unroll
    for (int rt = 0; rt < 4; ++rt)
#pragma unroll
        for (int ct = 0; ct < CT; ++ct) acc[rt][ct] = (f32x4){0.f, 0.f, 0.f, 0.f};

#pragma unroll
    for (int ks = 0; ks < 6; ++ks) {
        int kk = ks * 32 + g * 8;
        bf16x8 zfrag[4];
#pragma unroll
        for (int rt = 0; rt < 4; ++rt) {
            int n = nodebase + rt * 16 + l15;
            if (n >= N_NODES) n = N_NODES - 1;
            const unsigned short* p = (kk < 128)
                ? (s01b + (size_t)n * 128 + kk)
                : (featb + (size_t)n * 64 + (kk - 128));
            zfrag[rt] = *reinterpret_cast<const bf16x8*>(p);
        }
        bf16x8 wfrag[CT];
#pragma unroll
        for (int ct = 0; ct < CT; ++ct)
            wfrag[ct] = *reinterpret_cast<const bf16x8*>(Wt + (size_t)(ct * 16 + l15) * 192 + kk);
#pragma unroll
        for (int rt = 0; rt < 4; ++rt)
#pragma unroll
            for (int ct = 0; ct < CT; ++ct)
                acc[rt][ct] = __builtin_amdgcn_mfma_f32_16x16x32_bf16(
                    wfrag[ct], zfrag[rt], acc[rt][ct], 0, 0, 0);
    }

    f32x4 bv[CT];
#pragma unroll
    for (int ct = 0; ct < CT; ++ct) {
        int base = ct * 16 + g * 4;
        if (base + 4 <= COUT) {
            float4 b = *reinterpret_cast<const float4*>(bias + base);
            bv[ct] = (f32x4){b.x, b.y, b.z, b.w};
        } else {
            bv[ct] = (f32x4){0.f, 0.f, 0.f, 0.f};
        }
    }

    if (ACT == 1) {
        unsigned short* out = (unsigned short*)outv;
#pragma unroll
        for (int rt = 0; rt < 4; ++rt) {
            int n = nodebase + rt * 16 + l15;
            if (n >= N_NODES) continue;
#pragma unroll
            for (int ct = 0; ct < CT; ++ct) {
                f32x4 v = acc[rt][ct] + bv[ct];
                ushort4 o;
                float e;
                e = v[0]; o.x = f2bf(e > 0.f ? e : expm1f(e));
                e = v[1]; o.y = f2bf(e > 0.f ? e : expm1f(e));
                e = v[2]; o.z = f2bf(e > 0.f ? e : expm1f(e));
                e = v[3]; o.w = f2bf(e > 0.f ? e : expm1f(e));
                *reinterpret_cast<ushort4*>(out + (size_t)n * 64 + ct * 16 + g * 4) = o;
            }
        }
    } else {
        float* out = (float*)outv;
#pragma unroll
        for (int rt = 0; rt < 4; ++rt) {
            int n = nodebase + rt * 16 + l15;
            float v[CT * 4];
            float m = -3.4e38f;
#pragma unroll
            for (int ct = 0; ct < CT; ++ct)
#pragma unroll
                for (int r = 0; r < 4; ++r) {
                    int ch = ct * 16 + g * 4 + r;
                    float t = acc[rt][ct][r] + bv[ct][r];
                    v[ct * 4 + r] = t;
                    if (ch < COUT) m = fmaxf(m, t);
                }
            m = fmaxf(m, __shfl_xor(m, 16));
            m = fmaxf(m, __shfl_xor(m, 32));
            float s = 0.0f;
#pragma unroll
            for (int ct = 0; ct < CT; ++ct)
#pragma unroll
                for (int r = 0; r < 4; ++r) {
                    int ch = ct * 16 + g * 4 + r;
                    if (ch < COUT) s += expf(v[ct * 4 + r] - m);
                }
            s += __shfl_xor(s, 16);
            s += __shfl_xor(s, 32);
            float lse = m + logf(s);
            if (n >= N_NODES) continue;
#pragma unroll
            for (int ct = 0; ct < CT; ++ct) {
                int base = ct * 16 + g * 4;
                if (base + 4 <= COUT) {
                    float4 o;
                    o.x = v[ct * 4 + 0] - lse;
                    o.y = v[ct * 4 + 1] - lse;
                    o.z = v[ct * 4 + 2] - lse;
                    o.w = v[ct * 4 + 3] - lse;
                    *reinterpret_cast<float4*>(out + (size_t)n * COUT + base) = o;
                }
            }
        }
    }
}

extern "C" void kernel_launch(void* const* d_in, const int* in_sizes, int n_in,
                              void* d_out, int out_size, void* d_ws, size_t ws_size,
                              hipStream_t stream) {
    const float* x     = (const float*)d_in[0];
    const int*   ei    = (const int*)d_in[1];
    const float* ea    = (const float*)d_in[2];
    const float* W1    = (const float*)d_in[3];
    const float* root1 = (const float*)d_in[4];
    const float* b1    = (const float*)d_in[5];
    const float* W2    = (const float*)d_in[6];
    const float* root2 = (const float*)d_in[7];
    const float* b2    = (const float*)d_in[8];
    float* out = (float*)d_out;

    // workspace layout
    char* p = (char*)d_ws;
    int*   bucket_cur = (int*)p;            p += 512 * 4;
    int2*  binned  = (int2*)p;              p += (size_t)NBUK * BSTRIDE * 8;
    unsigned* rec  = (unsigned*)p;          p += (size_t)N_EDGES * 4;
    int*   rowptr  = (int*)p;               p += (size_t)N_NODES * 4;
    int*   cnt     = (int*)p;               p += (size_t)N_NODES * 4;
    unsigned short* s01b = (unsigned short*)p;  p += (size_t)N_NODES * 128 * 2;
    unsigned short* xb   = (unsigned short*)p;  p += (size_t)N_NODES * 64 * 2;
    unsigned short* hprb = (unsigned short*)p;  p += (size_t)N_NODES * 64 * 2;
    unsigned short* Wt1  = (unsigned short*)p;  p += (size_t)64 * 192 * 2;
    unsigned short* Wt2  = (unsigned short*)p;  p += (size_t)48 * 192 * 2;

    // ---- prep ----
    x2bf16_kernel<<<(N_NODES * 16) / 256, 256, 0, stream>>>(x, xb);
    wt_all<<<84, 256, 0, stream>>>(W1, root1, W2, root2, Wt1, Wt2);
    hipMemsetAsync(bucket_cur, 0, 512 * 4, stream);

    // ---- CSR build: 2-phase counting sort, key = (dst, src_tile/8) ----
    bin_edges<<<NCHA, 256, 0, stream>>>(ei, ea, bucket_cur, binned);
    bucket_sort<<<NBUK, 512, 0, stream>>>(bucket_cur, binned, rec, rowptr, cnt);

    // ---- layer 1 ----  (wave = 8 nodes -> 3125 blocks)
    pull_agg<<<(N_NODES + 31) / 32, 256, 0, stream>>>(rowptr, cnt, rec, xb, s01b);
    gemm_mfma<64, 4, 1><<<NB_SCAN, 256, 0, stream>>>(s01b, xb, Wt1, b1, hprb);

    // ---- layer 2 ----
    pull_agg<<<(N_NODES + 31) / 32, 256, 0, stream>>>(rowptr, cnt, rec, hprb, s01b);
    gemm_mfma<40, 3, 2><<<NB_SCAN, 256, 0, stream>>>(s01b, hprb, Wt2, b2, out);
}